// Round 9
// baseline (34.162 us; speedup 1.0000x reference)
//
#include <hip/hip_runtime.h>

#define HWD    48400          // 220*220
#define PATCHD 75
#define NPOS   96800          // 2 * HWD
#define KPAD   96             // padded K per half (3 MFMA K-steps of 32)

typedef __attribute__((ext_vector_type(8))) _Float16 f16x8;
typedef __attribute__((ext_vector_type(2))) __fp16   h16x2;   // cvt_pkrtz return type
typedef __attribute__((ext_vector_type(4))) float    f32x4;

union U2 { h16x2 h; unsigned u; };
union UF { unsigned u[4]; f16x8 v; };

// ---------------------------------------------------------------------------
// Table build: tbl[role][c][k], f16, k-major, zero-padded to KPAD.
//   role 0 = exp(k1), 1 = k1*exp(k1), 2 = exp(k2), 3 = k2*exp(k2)
// ---------------------------------------------------------------------------
__global__ void smorph_build_tables(const float* __restrict__ k1,
                                    const float* __restrict__ k2,
                                    _Float16* __restrict__ tbl)
{
    int i = (int)blockIdx.x * 256 + (int)threadIdx.x;   // (dir, c, k)
    if (i >= 2 * 16 * KPAD) return;
    int dir = i / (16 * KPAD);
    int r   = i - dir * (16 * KPAD);
    int c   = r / KPAD;
    int k   = r - c * KPAD;
    const float* kw = dir ? k2 : k1;
    float a = 0.f, b = 0.f;
    if (k < PATCHD) {
        float w = kw[k * 16 + c];
        float e = __expf(w);
        a = e;
        b = w * e;
    }
    tbl[(dir * 2 + 0) * (16 * KPAD) + c * KPAD + k] = (_Float16)a;
    tbl[(dir * 2 + 1) * (16 * KPAD) + c * KPAD + k] = (_Float16)b;
}

// ---------------------------------------------------------------------------
// INSTRUMENTATION VARIANT of round-8 body: repeated nrep times with an opaque
// per-repeat pointer offset (rep_off == 0 at runtime) so the compiler cannot
// CSE/hoist the repeats. Stores write identical values every repeat ->
// deterministic, harness-safe. Purpose: push dur above the ~40us poison
// fills so rocprof's top-5 exposes this kernel's counters.
// ---------------------------------------------------------------------------
__global__ __launch_bounds__(256, 4)
void smorph_mfma5r(const float* __restrict__ x,
                   const _Float16* __restrict__ tbl,
                   const float* __restrict__ bias,
                   float* __restrict__ out,
                   int nrep, long rep_off)
{
    const int tid = (int)threadIdx.x;
    const int l   = tid & 63;
    const int w   = tid >> 6;
    const int g   = l >> 4;         // k-subgroup 0..3
    const int c   = l & 15;         // channel lane (A) / position lane (B,D)
    const int p0  = (int)blockIdx.x * 64 + w * 16;
    if (p0 >= NPOS) return;         // no barriers anywhere -> safe
    const int b   = (p0 >= HWD) ? 1 : 0;   // HWD % 16 == 0: no straddle
    const int hw0 = p0 - b * HWD;

    const float* xb0 = x + (size_t)b * PATCHD * HWD + hw0 + c;

    for (int rep = 0; rep < nrep; ++rep) {
        const float*    xb = xb0 + rep * rep_off;     // opaque: defeats CSE
        const _Float16* t0 = tbl + c * KPAD + rep * rep_off;

        // ---- issue ALL x loads first: 3 steps x 8, clamped to k=74 ----
        float xv[3][8];
        #pragma unroll
        for (int s = 0; s < 3; ++s)
            #pragma unroll
            for (int j = 0; j < 8; ++j) {
                int k = 32 * s + 8 * g + j;
                k = (k > PATCHD - 1) ? (PATCHD - 1) : k;
                xv[s][j] = xb[(size_t)k * HWD];
            }

        f32x4 aN1 = {0.f,0.f,0.f,0.f}, aD1 = {0.f,0.f,0.f,0.f};
        f32x4 aN2 = {0.f,0.f,0.f,0.f}, aD2 = {0.f,0.f,0.f,0.f};

        #pragma unroll
        for (int s = 0; s < 3; ++s) {
            UF a1f, b1f, a2f, b2f;
            #pragma unroll
            for (int jp = 0; jp < 4; ++jp) {
                const int off = 32 * s + 8 * g + 2 * jp;
                a1f.u[jp] = *(const unsigned*)(t0 + 0 * 16 * KPAD + off);
                b1f.u[jp] = *(const unsigned*)(t0 + 1 * 16 * KPAD + off);
                a2f.u[jp] = *(const unsigned*)(t0 + 2 * 16 * KPAD + off);
                b2f.u[jp] = *(const unsigned*)(t0 + 3 * 16 * KPAD + off);
            }

            float E[8], R[8];
            #pragma unroll
            for (int j = 0; j < 8; ++j) {
                E[j] = __expf(xv[s][j]);
                R[j] = __expf(-xv[s][j]);
            }

            UF fEx, fE, fRx, fR;
            #pragma unroll
            for (int jp = 0; jp < 4; ++jp) {
                const float x0 = xv[s][2*jp], x1 = xv[s][2*jp+1];
                U2 q;
                q.h = __builtin_amdgcn_cvt_pkrtz(E[2*jp] * x0,  E[2*jp+1] * x1);  fEx.u[jp] = q.u;
                q.h = __builtin_amdgcn_cvt_pkrtz(E[2*jp],       E[2*jp+1]);       fE.u[jp]  = q.u;
                q.h = __builtin_amdgcn_cvt_pkrtz(-R[2*jp] * x0, -R[2*jp+1] * x1); fRx.u[jp] = q.u;
                q.h = __builtin_amdgcn_cvt_pkrtz(R[2*jp],       R[2*jp+1]);       fR.u[jp]  = q.u;
            }

            aN1 = __builtin_amdgcn_mfma_f32_16x16x32_f16(a1f.v, fEx.v, aN1, 0, 0, 0);
            aN1 = __builtin_amdgcn_mfma_f32_16x16x32_f16(b1f.v, fE.v,  aN1, 0, 0, 0);
            aD1 = __builtin_amdgcn_mfma_f32_16x16x32_f16(a1f.v, fE.v,  aD1, 0, 0, 0);
            aN2 = __builtin_amdgcn_mfma_f32_16x16x32_f16(a2f.v, fRx.v, aN2, 0, 0, 0);
            aN2 = __builtin_amdgcn_mfma_f32_16x16x32_f16(b2f.v, fR.v,  aN2, 0, 0, 0);
            aD2 = __builtin_amdgcn_mfma_f32_16x16x32_f16(a2f.v, fR.v,  aD2, 0, 0, 0);
        }

        const float4 bsv = *(const float4*)(bias + 4 * g);
        float* ob = out + ((size_t)(b * 16 + 4 * g)) * HWD + hw0 + c;
        ob[0 * (size_t)HWD] = aN1[0] * __builtin_amdgcn_rcpf(aD1[0]) + aN2[0] * __builtin_amdgcn_rcpf(aD2[0]) + bsv.x;
        ob[1 * (size_t)HWD] = aN1[1] * __builtin_amdgcn_rcpf(aD1[1]) + aN2[1] * __builtin_amdgcn_rcpf(aD2[1]) + bsv.y;
        ob[2 * (size_t)HWD] = aN1[2] * __builtin_amdgcn_rcpf(aD1[2]) + aN2[2] * __builtin_amdgcn_rcpf(aD2[2]) + bsv.z;
        ob[3 * (size_t)HWD] = aN1[3] * __builtin_amdgcn_rcpf(aD1[3]) + aN2[3] * __builtin_amdgcn_rcpf(aD2[3]) + bsv.w;
    }
}

extern "C" void kernel_launch(void* const* d_in, const int* in_sizes, int n_in,
                              void* d_out, int out_size, void* d_ws, size_t ws_size,
                              hipStream_t stream)
{
    const float* x    = (const float*)d_in[0];
    const float* k1   = (const float*)d_in[1];
    const float* k2   = (const float*)d_in[2];
    const float* bias = (const float*)d_in[3];
    float* out = (float*)d_out;
    _Float16* tbl = (_Float16*)d_ws;     // 12 KB

    smorph_build_tables<<<(2 * 16 * KPAD + 255) / 256, 256, 0, stream>>>(k1, k2, tbl);
    // nrep=4, rep_off=0: 4x redundant compute, identical stores -> visible counters
    smorph_mfma5r<<<(NPOS + 63) / 64, 256, 0, stream>>>(x, tbl, bias, out, 4, 0L);
}

// Round 10
// 18.178 us; speedup vs baseline: 1.8793x; 1.8793x over previous
//
#include <hip/hip_runtime.h>

#define HWD    48400          // 220*220
#define PATCHD 75
#define NPOS   96800          // 2 * HWD

typedef __attribute__((ext_vector_type(8))) _Float16 f16x8;
typedef __attribute__((ext_vector_type(2))) __fp16   h16x2;   // cvt_pkrtz return type
typedef __attribute__((ext_vector_type(4))) float    f32x4;

union U2 { h16x2 h; unsigned u; };
union UF { unsigned u[4]; f16x8 v; };

// ---------------------------------------------------------------------------
// Table build, FRAGMENT-MAJOR layout:
//   tbl[((t*4 + g)*16 + c)*8 + j],  t = role*3 + s,  k = 32s + 8g + j
//   role 0 = exp(k1), 1 = k1*exp(k1), 2 = exp(k2), 3 = k2*exp(k2); k>=75 -> 0
// A wave's fragment read (lane (g,c), 8 f16) is then 64 x 16B CONTIGUOUS:
// one global_load_dwordx4, 16 cachelines -- vs 192B lane-stride (64 lines) before.
// Total 12 KB in d_ws.
// ---------------------------------------------------------------------------
__global__ void smorph_build_tables(const float* __restrict__ k1,
                                    const float* __restrict__ k2,
                                    _Float16* __restrict__ tbl)
{
    int i = (int)blockIdx.x * 256 + (int)threadIdx.x;   // 6144 entries
    if (i >= 4 * 3 * 4 * 16 * 8) return;
    const int j = i & 7;
    const int c = (i >> 3) & 15;
    const int g = (i >> 7) & 3;
    const int t = i >> 9;          // 0..11 = role*3 + s
    const int s = t % 3;
    const int r = t / 3;
    const int k = 32 * s + 8 * g + j;
    float val = 0.f;
    if (k < PATCHD) {
        const float* kw = (r < 2) ? k1 : k2;
        const float w = kw[k * 16 + c];
        const float e = __expf(w);
        val = (r & 1) ? (w * e) : e;
    }
    tbl[i] = (_Float16)val;        // i == ((t*4+g)*16+c)*8 + j by construction
}

// ---------------------------------------------------------------------------
// Main: straight-line, no LDS, no barriers. 24 upfront x loads (clamped at
// k>=75; zero table rows annihilate them). Per K-step: 4 coalesced dwordx4
// table loads, 16 exp, 16 muls, 16 packs, 6 MFMA.
// ---------------------------------------------------------------------------
__global__ __launch_bounds__(256, 4)
void smorph_mfma6(const float* __restrict__ x,
                  const _Float16* __restrict__ tbl,
                  const float* __restrict__ bias,
                  float* __restrict__ out)
{
    const int tid = (int)threadIdx.x;
    const int l   = tid & 63;
    const int w   = tid >> 6;
    const int g   = l >> 4;         // k-subgroup 0..3
    const int c   = l & 15;         // channel lane (A) / position lane (B,D)
    const int p0  = (int)blockIdx.x * 64 + w * 16;
    if (p0 >= NPOS) return;         // no barriers anywhere -> safe
    const int b   = (p0 >= HWD) ? 1 : 0;   // HWD % 16 == 0: no straddle
    const int hw0 = p0 - b * HWD;

    const float* xb = x + (size_t)b * PATCHD * HWD + hw0 + c;
    const f16x8* tf = (const f16x8*)tbl;
    const int fbase = g * 16 + c;   // lane-linear within each 64-frag group

    // ---- issue ALL x loads first: 3 steps x 8, addresses clamped to k=74 ----
    float xv[3][8];
    #pragma unroll
    for (int s = 0; s < 3; ++s)
        #pragma unroll
        for (int j = 0; j < 8; ++j) {
            int k = 32 * s + 8 * g + j;
            k = (k > PATCHD - 1) ? (PATCHD - 1) : k;   // only s==2 clamps
            xv[s][j] = xb[(size_t)k * HWD];
        }

    f32x4 aN1 = {0.f,0.f,0.f,0.f}, aD1 = {0.f,0.f,0.f,0.f};
    f32x4 aN2 = {0.f,0.f,0.f,0.f}, aD2 = {0.f,0.f,0.f,0.f};

    #pragma unroll
    for (int s = 0; s < 3; ++s) {
        // 4 coalesced dwordx4 fragment loads (wave reads 4x1KB contiguous)
        const f16x8 a1f = tf[(0 * 3 + s) * 64 + fbase];
        const f16x8 b1f = tf[(1 * 3 + s) * 64 + fbase];
        const f16x8 a2f = tf[(2 * 3 + s) * 64 + fbase];
        const f16x8 b2f = tf[(3 * 3 + s) * 64 + fbase];

        float E[8], R[8];
        #pragma unroll
        for (int j = 0; j < 8; ++j) {
            E[j] = __expf(xv[s][j]);
            R[j] = __expf(-xv[s][j]);
        }

        UF fEx, fE, fRx, fR;
        #pragma unroll
        for (int jp = 0; jp < 4; ++jp) {
            const float x0 = xv[s][2*jp], x1 = xv[s][2*jp+1];
            U2 q;
            q.h = __builtin_amdgcn_cvt_pkrtz(E[2*jp] * x0,  E[2*jp+1] * x1);  fEx.u[jp] = q.u;
            q.h = __builtin_amdgcn_cvt_pkrtz(E[2*jp],       E[2*jp+1]);       fE.u[jp]  = q.u;
            q.h = __builtin_amdgcn_cvt_pkrtz(-R[2*jp] * x0, -R[2*jp+1] * x1); fRx.u[jp] = q.u;
            q.h = __builtin_amdgcn_cvt_pkrtz(R[2*jp],       R[2*jp+1]);       fR.u[jp]  = q.u;
        }

        aN1 = __builtin_amdgcn_mfma_f32_16x16x32_f16(a1f, fEx.v, aN1, 0, 0, 0);
        aN1 = __builtin_amdgcn_mfma_f32_16x16x32_f16(b1f, fE.v,  aN1, 0, 0, 0);
        aD1 = __builtin_amdgcn_mfma_f32_16x16x32_f16(a1f, fE.v,  aD1, 0, 0, 0);
        aN2 = __builtin_amdgcn_mfma_f32_16x16x32_f16(a2f, fRx.v, aN2, 0, 0, 0);
        aN2 = __builtin_amdgcn_mfma_f32_16x16x32_f16(b2f, fR.v,  aN2, 0, 0, 0);
        aD2 = __builtin_amdgcn_mfma_f32_16x16x32_f16(a2f, fR.v,  aD2, 0, 0, 0);
    }

    // ---- epilogue: y = num1/den1 + num2/den2 + bias; 64B-segment stores ----
    const float4 bsv = *(const float4*)(bias + 4 * g);
    float* ob = out + ((size_t)(b * 16 + 4 * g)) * HWD + hw0 + c;
    ob[0 * (size_t)HWD] = aN1[0] * __builtin_amdgcn_rcpf(aD1[0]) + aN2[0] * __builtin_amdgcn_rcpf(aD2[0]) + bsv.x;
    ob[1 * (size_t)HWD] = aN1[1] * __builtin_amdgcn_rcpf(aD1[1]) + aN2[1] * __builtin_amdgcn_rcpf(aD2[1]) + bsv.y;
    ob[2 * (size_t)HWD] = aN1[2] * __builtin_amdgcn_rcpf(aD1[2]) + aN2[2] * __builtin_amdgcn_rcpf(aD2[2]) + bsv.z;
    ob[3 * (size_t)HWD] = aN1[3] * __builtin_amdgcn_rcpf(aD1[3]) + aN2[3] * __builtin_amdgcn_rcpf(aD2[3]) + bsv.w;
}

extern "C" void kernel_launch(void* const* d_in, const int* in_sizes, int n_in,
                              void* d_out, int out_size, void* d_ws, size_t ws_size,
                              hipStream_t stream)
{
    const float* x    = (const float*)d_in[0];
    const float* k1   = (const float*)d_in[1];
    const float* k2   = (const float*)d_in[2];
    const float* bias = (const float*)d_in[3];
    float* out = (float*)d_out;
    _Float16* tbl = (_Float16*)d_ws;     // 12 KB, fragment-major

    smorph_build_tables<<<(4 * 3 * 4 * 16 * 8 + 255) / 256, 256, 0, stream>>>(k1, k2, tbl);
    smorph_mfma6<<<(NPOS + 63) / 64, 256, 0, stream>>>(x, tbl, bias, out);
}

// Round 11
// 17.536 us; speedup vs baseline: 1.9481x; 1.0366x over previous
//
#include <hip/hip_runtime.h>

#define HWD    48400          // 220*220
#define PATCHD 75
#define NPOS   96800          // 2 * HWD
#define NTILE  1513           // ceil(NPOS/64)
#define GRID   512            // persistent blocks: 2 per CU

typedef __attribute__((ext_vector_type(8))) _Float16 f16x8;
typedef __attribute__((ext_vector_type(2))) __fp16   h16x2;   // cvt_pkrtz return type
typedef __attribute__((ext_vector_type(4))) float    f32x4;

union U2 { h16x2 h; unsigned u; };
union UF { unsigned u[4]; f16x8 v; };

// ---------------------------------------------------------------------------
// Table build, FRAGMENT-MAJOR layout (unchanged from round 10):
//   tbl[((t*4 + g)*16 + c)*8 + j],  t = role*3 + s,  k = 32s + 8g + j
//   role 0 = exp(k1), 1 = k1*exp(k1), 2 = exp(k2), 3 = k2*exp(k2); k>=75 -> 0
// ---------------------------------------------------------------------------
__global__ void smorph_build_tables(const float* __restrict__ k1,
                                    const float* __restrict__ k2,
                                    _Float16* __restrict__ tbl)
{
    int i = (int)blockIdx.x * 256 + (int)threadIdx.x;   // 6144 entries
    if (i >= 4 * 3 * 4 * 16 * 8) return;
    const int j = i & 7;
    const int c = (i >> 3) & 15;
    const int g = (i >> 7) & 3;
    const int t = i >> 9;          // 0..11 = role*3 + s
    const int s = t % 3;
    const int r = t / 3;
    const int k = 32 * s + 8 * g + j;
    float val = 0.f;
    if (k < PATCHD) {
        const float* kw = (r < 2) ? k1 : k2;
        const float w = kw[k * 16 + c];
        const float e = __expf(w);
        val = (r & 1) ? (w * e) : e;
    }
    tbl[i] = (_Float16)val;
}

// ---------------------------------------------------------------------------
// Persistent pipelined main kernel: each block owns tiles {bid, bid+512, ...}.
// While tile t computes, tile t+512's 24 x-loads are in flight (A/B ping-pong,
// fully static register buffers). No LDS, no barriers, no spills (cap 256).
// ---------------------------------------------------------------------------
__global__ __launch_bounds__(256, 2)
void smorph_mfma7(const float* __restrict__ x,
                  const _Float16* __restrict__ tbl,
                  const float* __restrict__ bias,
                  float* __restrict__ out)
{
    const int tid = (int)threadIdx.x;
    const int l   = tid & 63;
    const int w   = tid >> 6;
    const int g   = l >> 4;         // k-subgroup 0..3
    const int c   = l & 15;         // channel lane (A) / position lane (B,D)

    // ---- table fragments -> registers, once (12 coalesced dwordx4) ----
    const f16x8* tf = (const f16x8*)tbl;
    const int fbase = g * 16 + c;
    f16x8 Tf[12];
    #pragma unroll
    for (int t = 0; t < 12; ++t) Tf[t] = tf[t * 64 + fbase];

    const float4 bsv = *(const float4*)(bias + 4 * g);

    // ---- issue 24 x-loads for tile `tt` into dst[24] (k clamped; zero rows kill pad) ----
    #define LOADX(dst, tt)                                                    \
        {                                                                     \
            int p0b_ = (tt) * 64;                                             \
            if (p0b_ > NPOS - 64) p0b_ = NPOS - 64;                           \
            const int p0_ = p0b_ + w * 16;                                    \
            const int bb_ = (p0_ >= HWD) ? 1 : 0;                             \
            const float* xb_ = x + (size_t)bb_ * PATCHD * HWD                 \
                               + (p0_ - bb_ * HWD) + c;                       \
            _Pragma("unroll")                                                 \
            for (int s_ = 0; s_ < 3; ++s_)                                    \
                _Pragma("unroll")                                             \
                for (int j_ = 0; j_ < 8; ++j_) {                              \
                    int k_ = 32 * s_ + 8 * g + j_;                            \
                    k_ = (k_ > PATCHD - 1) ? (PATCHD - 1) : k_;               \
                    (dst)[s_ * 8 + j_] = xb_[(size_t)k_ * HWD];               \
                }                                                             \
        }

    // ---- compute + store tile `tt` from src[24] ----
    #define COMPSTORE(src, tt)                                                \
        {                                                                     \
            f32x4 aN1 = {0.f,0.f,0.f,0.f}, aD1 = {0.f,0.f,0.f,0.f};          \
            f32x4 aN2 = {0.f,0.f,0.f,0.f}, aD2 = {0.f,0.f,0.f,0.f};          \
            _Pragma("unroll")                                                 \
            for (int s_ = 0; s_ < 3; ++s_) {                                  \
                float E[8], R[8];                                             \
                _Pragma("unroll")                                             \
                for (int j_ = 0; j_ < 8; ++j_) {                              \
                    E[j_] = __expf((src)[s_ * 8 + j_]);                       \
                    R[j_] = __expf(-(src)[s_ * 8 + j_]);                      \
                }                                                             \
                UF fEx, fE, fRx, fR;                                          \
                _Pragma("unroll")                                             \
                for (int jp = 0; jp < 4; ++jp) {                              \
                    const float x0 = (src)[s_ * 8 + 2 * jp];                  \
                    const float x1 = (src)[s_ * 8 + 2 * jp + 1];              \
                    U2 q;                                                     \
                    q.h = __builtin_amdgcn_cvt_pkrtz(E[2*jp] * x0,  E[2*jp+1] * x1);  fEx.u[jp] = q.u; \
                    q.h = __builtin_amdgcn_cvt_pkrtz(E[2*jp],       E[2*jp+1]);       fE.u[jp]  = q.u; \
                    q.h = __builtin_amdgcn_cvt_pkrtz(-R[2*jp] * x0, -R[2*jp+1] * x1); fRx.u[jp] = q.u; \
                    q.h = __builtin_amdgcn_cvt_pkrtz(R[2*jp],       R[2*jp+1]);       fR.u[jp]  = q.u; \
                }                                                             \
                aN1 = __builtin_amdgcn_mfma_f32_16x16x32_f16(Tf[0 + s_], fEx.v, aN1, 0, 0, 0); \
                aN1 = __builtin_amdgcn_mfma_f32_16x16x32_f16(Tf[3 + s_], fE.v,  aN1, 0, 0, 0); \
                aD1 = __builtin_amdgcn_mfma_f32_16x16x32_f16(Tf[0 + s_], fE.v,  aD1, 0, 0, 0); \
                aN2 = __builtin_amdgcn_mfma_f32_16x16x32_f16(Tf[6 + s_], fRx.v, aN2, 0, 0, 0); \
                aN2 = __builtin_amdgcn_mfma_f32_16x16x32_f16(Tf[9 + s_], fR.v,  aN2, 0, 0, 0); \
                aD2 = __builtin_amdgcn_mfma_f32_16x16x32_f16(Tf[6 + s_], fR.v,  aD2, 0, 0, 0); \
            }                                                                 \
            int p0b_ = (tt) * 64;                                             \
            if (p0b_ > NPOS - 64) p0b_ = NPOS - 64;                           \
            const int p0_ = p0b_ + w * 16;                                    \
            const int bb_ = (p0_ >= HWD) ? 1 : 0;                             \
            const int hw0_ = p0_ - bb_ * HWD;                                 \
            float* ob_ = out + ((size_t)(bb_ * 16 + 4 * g)) * HWD + hw0_ + c; \
            ob_[0 * (size_t)HWD] = aN1[0] * __builtin_amdgcn_rcpf(aD1[0]) + aN2[0] * __builtin_amdgcn_rcpf(aD2[0]) + bsv.x; \
            ob_[1 * (size_t)HWD] = aN1[1] * __builtin_amdgcn_rcpf(aD1[1]) + aN2[1] * __builtin_amdgcn_rcpf(aD2[1]) + bsv.y; \
            ob_[2 * (size_t)HWD] = aN1[2] * __builtin_amdgcn_rcpf(aD1[2]) + aN2[2] * __builtin_amdgcn_rcpf(aD2[2]) + bsv.z; \
            ob_[3 * (size_t)HWD] = aN1[3] * __builtin_amdgcn_rcpf(aD1[3]) + aN2[3] * __builtin_amdgcn_rcpf(aD2[3]) + bsv.w; \
        }

    // ---- persistent A/B-pipelined tile loop (all branches block-uniform) ----
    float xva[24], xvb[24];
    int t = (int)blockIdx.x;        // t < GRID <= NTILE always
    LOADX(xva, t);
    while (true) {
        int tn = t + GRID;
        if (tn < NTILE) {
            LOADX(xvb, tn);         // prefetch under compute of t
            COMPSTORE(xva, t);
            t = tn;
        } else {
            COMPSTORE(xva, t);
            break;
        }
        tn = t + GRID;
        if (tn < NTILE) {
            LOADX(xva, tn);         // prefetch under compute of t
            COMPSTORE(xvb, t);
            t = tn;
        } else {
            COMPSTORE(xvb, t);
            break;
        }
    }
    #undef LOADX
    #undef COMPSTORE
}

extern "C" void kernel_launch(void* const* d_in, const int* in_sizes, int n_in,
                              void* d_out, int out_size, void* d_ws, size_t ws_size,
                              hipStream_t stream)
{
    const float* x    = (const float*)d_in[0];
    const float* k1   = (const float*)d_in[1];
    const float* k2   = (const float*)d_in[2];
    const float* bias = (const float*)d_in[3];
    float* out = (float*)d_out;
    _Float16* tbl = (_Float16*)d_ws;     // 12 KB, fragment-major

    smorph_build_tables<<<(4 * 3 * 4 * 16 * 8 + 255) / 256, 256, 0, stream>>>(k1, k2, tbl);
    smorph_mfma7<<<GRID, 256, 0, stream>>>(x, tbl, bias, out);
}